// Round 6
// baseline (115.269 us; speedup 1.0000x reference)
//
#include <hip/hip_runtime.h>
#include <hip/hip_bf16.h>
#include <math.h>

#define NBINS   129
#define NFFT    256
#define WINL    768
#define TFRAMES 4096
#define OUTL    523640          // 4096*128 - 648
#define SHIFT   648
#define WSEG    26
#define CHUNK   (WSEG * 128)    // 3328 output samples per block
#define NCHUNK  ((OUTL + CHUNK - 1) / CHUNK)   // 158
#define FF      32              // frames staged per block (WSEG + 6)

#define KDIM    288             // 258 real K padded to 9*32
#define KROW    296             // B row stride (ushorts); KROW%8==0 for b128 frags
#define GROW    268             // bf16 G row stride (536 B)
#define WBYTES  (16 * 9 * 64 * 16)   // 147456 B packed twiddles
#define NSTG    17              // ceil(129*32 / 256) staging iters

typedef __attribute__((ext_vector_type(8))) short bf16x8;   // 8 bf16 = 4 VGPR
typedef __attribute__((ext_vector_type(4))) float f32x4;

static __device__ __forceinline__ ushort f2bf(float x) {
    union { float f; unsigned u; } v; v.f = x;
    unsigned r = v.u + 0x7FFFu + ((v.u >> 16) & 1u);   // RTN-even
    return (ushort)(r >> 16);
}

// ---- pre-kernel: W[m][kappa] packed in mfma A-fragment order ----------------
__global__ void build_w_kernel(ushort* __restrict__ wp)
{
    const int gid  = blockIdx.x * 256 + threadIdx.x;    // 0..9215
    const int lane = gid & 63;
    const int mtks = gid >> 6;                          // 0..143
    const int ks   = mtks % 9;
    const int mt   = mtks / 9;
    const int m    = mt * 16 + (lane & 15);
    const int kb   = ks * 32 + ((lane >> 4) << 3);

    ushort o[8];
    #pragma unroll
    for (int e = 0; e < 8; ++e) {
        const int kap = kb + e;
        float val = 0.f;
        if (kap < 258) {
            const int k = kap >> 1;
            float s, c;
            sincospif((float)(k * (m + 1)) * (1.0f / 128.0f), &s, &c);
            if (kap & 1)  val = (k >= 1 && k <= 127) ? s * (2.0f / 256.0f) : 0.f;
            else          val = (k == 0 || k == 128) ? c * (1.0f / 256.0f)
                                                     : c * (2.0f / 256.0f);
        }
        o[e] = f2bf(val);
    }
    int4 pk;
    pk.x = o[0] | (o[1] << 16); pk.y = o[2] | (o[3] << 16);
    pk.z = o[4] | (o[5] << 16); pk.w = o[6] | (o[7] << 16);
    ((int4*)wp)[gid] = pk;
}

// ---- main fused kernel: stage -> MFMA DFT -> overlap-add --------------------
__global__ __launch_bounds__(256, 6)
void pfb_mfma_kernel(const float* __restrict__ gre, const float* __restrict__ gim,
                     const float* __restrict__ glpf, const ushort* __restrict__ wp,
                     float* __restrict__ out)
{
    __shared__ ushort s_bufu[FF * KROW];   // 18944 B; B (bf16), later aliased by G
    ushort* s_Bu = s_bufu;
    ushort (*s_G)[GROW] = (ushort (*)[GROW])s_bufu;   // 32*268*2 = 17152 B

    const int q   = blockIdx.x;
    const int bc  = blockIdx.y;
    const int tid = threadIdx.x;
    const int t0  = WSEG * q;
    const size_t specBase = (size_t)bc * NBINS * TFRAMES;

    // ---- OA constants: s = i+648 = 128a + b; b invariant across r-iters ----
    const int s0 = q * CHUNK + tid + SHIFT;
    const int b  = s0 & 127;
    const int a0 = s0 >> 7;
    // 6 lpf weights, loaded once (global, L2-hot). tap p: lpf[128p + b]
    float lw[6];
    #pragma unroll
    for (int p = 0; p < 6; ++p) lw[p] = glpf[(p << 7) + b];

    // ---- stage: issue ALL 34 global loads first (deep MLP), then LDS writes
    float vr[NSTG], vi[NSTG];
    #pragma unroll
    for (int r = 0; r < NSTG; ++r) {
        const int idx = tid + r * 256;
        const int k = idx >> 5, f = idx & 31;
        const int t = t0 + f;
        const bool ok = (idx < NBINS * FF) && (t < TFRAMES);
        float a = 0.f, bb = 0.f;
        if (ok) {
            const size_t g = specBase + (size_t)k * TFRAMES + (size_t)t;
            a = gre[g]; bb = gim[g];
        }
        vr[r] = a; vi[r] = bb;
    }
    #pragma unroll
    for (int r = 0; r < NSTG; ++r) {
        const int idx = tid + r * 256;
        if (idx < NBINS * FF) {
            const int k = idx >> 5, f = idx & 31;
            __hip_bfloat162 p = __float22bfloat162_rn(make_float2(vr[r], vi[r]));
            *(__hip_bfloat162*)&s_Bu[f * KROW + 2 * k] = p;
        }
    }
    // zero-pad kappa = 258..295
    for (int idx = tid; idx < FF * (KROW - 258); idx += 256) {
        const int f = idx / (KROW - 258), r = idx - f * (KROW - 258);
        s_Bu[f * KROW + 258 + r] = 0;
    }
    __syncthreads();

    // ---- GEMM: G[256][32] = W[256][288] x B[288][32] ----
    const int lane = tid & 63;
    const int wid  = tid >> 6;
    const int brow = lane & 15;
    const int kgrp = (lane >> 4) << 3;

    bf16x8 bfrag[2][9];
    #pragma unroll
    for (int nt = 0; nt < 2; ++nt)
        #pragma unroll
        for (int ks = 0; ks < 9; ++ks)
            bfrag[nt][ks] = *(const bf16x8*)&s_Bu[(nt * 16 + brow) * KROW + ks * 32 + kgrp];

    f32x4 acc[4][2];
    #pragma unroll
    for (int mi = 0; mi < 4; ++mi)
        #pragma unroll
        for (int nt = 0; nt < 2; ++nt)
            acc[mi][nt] = (f32x4){0.f, 0.f, 0.f, 0.f};

    #pragma unroll 1
    for (int mi = 0; mi < 4; ++mi) {
        const ushort* wbase = wp + ((size_t)((wid * 4 + mi) * 9) * 64 + lane) * 8;
        #pragma unroll
        for (int ks = 0; ks < 9; ++ks) {
            const bf16x8 aw = *(const bf16x8*)(wbase + ks * 512);
            acc[mi][0] = __builtin_amdgcn_mfma_f32_16x16x32_bf16(aw, bfrag[0][ks], acc[mi][0], 0, 0, 0);
            acc[mi][1] = __builtin_amdgcn_mfma_f32_16x16x32_bf16(aw, bfrag[1][ks], acc[mi][1], 0, 0, 0);
        }
    }
    __syncthreads();   // B fully consumed; alias with s_G

    // D layout: col(frame) = lane&15, row(m) = (lane>>4)*4 + e  -> bf16x4 store
    #pragma unroll
    for (int mi = 0; mi < 4; ++mi) {
        const int m0 = (wid * 4 + mi) * 16 + ((lane >> 4) << 2);
        #pragma unroll
        for (int nt = 0; nt < 2; ++nt) {
            const int f = nt * 16 + brow;
            __hip_bfloat162 lo = __float22bfloat162_rn(make_float2(acc[mi][nt].x, acc[mi][nt].y));
            __hip_bfloat162 hi = __float22bfloat162_rn(make_float2(acc[mi][nt].z, acc[mi][nt].w));
            uint2 pk; pk.x = *(unsigned*)&lo; pk.y = *(unsigned*)&hi;
            *(uint2*)&s_G[f][m0] = pk;
        }
    }
    __syncthreads();

    // ---- overlap-add: out[i] = -32768 * sum_p lpf[128p+b] * G[a-p][b+128(p&1)]
    // Base row = a - t0 - 5 (>= 0 always); tap p at byte offset
    // (5-p)*2*GROW + (p&1)*256 from base — all compile-time immediates.
    const size_t outBase = (size_t)bc * OUTL;
    const ushort* gbase = &s_G[a0 - t0 - 5][b];   // advances 2 rows per r-iter
    int i = q * CHUNK + tid;
    #pragma unroll 1
    for (int r = 0; r < 13; ++r) {
        float sum = 0.f;
        #pragma unroll
        for (int p = 0; p < 6; ++p) {
            const ushort gu = gbase[(5 - p) * GROW + ((p & 1) << 7)];
            union { unsigned u_; float f; } g;
            g.u_ = ((unsigned)gu) << 16;          // bf16 -> f32
            sum += lw[p] * g.f;
        }
        if (i < OUTL) out[outBase + i] = sum * (-32768.0f);
        gbase += 2 * GROW;
        i += 256;
    }
}

// ---- fallback (round-1 f32 path, used only if ws too small) -----------------
__global__ __launch_bounds__(256, 2)
void pfb_fused_kernel(const float* __restrict__ gre, const float* __restrict__ gim,
                      const float* __restrict__ glpf, float* __restrict__ out)
{
    __shared__ float s_buf[NBINS * FF * 2];
    __shared__ float s_lpf[WINL];
    float (*s_re)[FF]  = (float (*)[FF])s_buf;
    float (*s_im)[FF]  = (float (*)[FF])(s_buf + NBINS * FF);
    float (*s_G)[NFFT] = (float (*)[NFFT])s_buf;

    const int q = blockIdx.x, bc = blockIdx.y, tid = threadIdx.x;
    const int t0 = WSEG * q;
    const size_t specBase = (size_t)bc * NBINS * TFRAMES;

    for (int idx = tid; idx < WINL; idx += 256) s_lpf[idx] = glpf[idx];
    for (int idx = tid; idx < NBINS * FF; idx += 256) {
        const int k = idx >> 5, f = idx & 31;
        const int t = t0 + f;
        float vr = 0.f, vi = 0.f;
        if (t < TFRAMES) {
            const size_t g = specBase + (size_t)k * TFRAMES + (size_t)t;
            vr = gre[g]; vi = gim[g];
        }
        s_re[k][f] = vr; s_im[k][f] = vi;
    }
    __syncthreads();

    const int ng = tid & 63, fg = tid >> 6, f0 = fg * 8;
    float cphi[4], sphi[4], cc[4], ss[4], acc[4][8];
    #pragma unroll
    for (int j = 0; j < 4; ++j) {
        const int m = ng + 64 * j;
        sincospif((float)(m + 1) * (1.0f / 128.0f), &sphi[j], &cphi[j]);
        cc[j] = 1.f; ss[j] = 0.f;
        #pragma unroll
        for (int f = 0; f < 8; ++f) acc[j][f] = 0.f;
    }
    #pragma unroll 2
    for (int k = 1; k <= 127; ++k) {
        const float4 rl = *(const float4*)&s_re[k][f0];
        const float4 rh = *(const float4*)&s_re[k][f0 + 4];
        const float4 il = *(const float4*)&s_im[k][f0];
        const float4 ih = *(const float4*)&s_im[k][f0 + 4];
        #pragma unroll
        for (int j = 0; j < 4; ++j) {
            const float c2 = cc[j] * cphi[j] - ss[j] * sphi[j];
            const float s2 = ss[j] * cphi[j] + cc[j] * sphi[j];
            cc[j] = c2; ss[j] = s2;
            acc[j][0] += rl.x * c2 + il.x * s2;
            acc[j][1] += rl.y * c2 + il.y * s2;
            acc[j][2] += rl.z * c2 + il.z * s2;
            acc[j][3] += rl.w * c2 + il.w * s2;
            acc[j][4] += rh.x * c2 + ih.x * s2;
            acc[j][5] += rh.y * c2 + ih.y * s2;
            acc[j][6] += rh.z * c2 + ih.z * s2;
            acc[j][7] += rh.w * c2 + ih.w * s2;
        }
    }
    float r0[8], r128[8];
    #pragma unroll
    for (int f = 0; f < 8; ++f) { r0[f] = s_re[0][f0 + f]; r128[f] = s_re[128][f0 + f]; }
    __syncthreads();
    #pragma unroll
    for (int j = 0; j < 4; ++j) {
        const int m = ng + 64 * j;
        const float sgn = (m & 1) ? 1.0f : -1.0f;
        #pragma unroll
        for (int f = 0; f < 8; ++f)
            s_G[f0 + f][m] = (r0[f] + 2.0f * acc[j][f] + sgn * r128[f]) * (1.0f / 256.0f);
    }
    __syncthreads();
    const size_t outBase = (size_t)bc * OUTL;
    const int i0 = q * CHUNK;
    #pragma unroll 1
    for (int r = 0; r < 13; ++r) {
        const int i = i0 + r * 256 + tid;
        if (i < OUTL) {
            const int s = i + SHIFT;
            int tlo = (s - 640) >> 7;  if (tlo < t0) tlo = t0;
            int thi = s >> 7;
            if (thi > t0 + FF - 1) thi = t0 + FF - 1;
            if (thi > TFRAMES - 1) thi = TFRAMES - 1;
            float sum = 0.f;
            for (int t = tlo; t <= thi; ++t) {
                const int jj = s - (t << 7);
                sum += s_lpf[jj] * s_G[t - t0][jj & 255];
            }
            out[outBase + i] = sum * (-32768.0f);
        }
    }
}

extern "C" void kernel_launch(void* const* d_in, const int* in_sizes, int n_in,
                              void* d_out, int out_size, void* d_ws, size_t ws_size,
                              hipStream_t stream)
{
    const float* gre  = (const float*)d_in[0];
    const float* gim  = (const float*)d_in[1];
    const float* glpf = (const float*)d_in[2];
    float* out = (float*)d_out;

    if (ws_size >= (size_t)WBYTES) {
        ushort* wp = (ushort*)d_ws;
        build_w_kernel<<<36, 256, 0, stream>>>(wp);
        dim3 grid(NCHUNK, 16);
        pfb_mfma_kernel<<<grid, 256, 0, stream>>>(gre, gim, glpf, wp, out);
    } else {
        dim3 grid(NCHUNK, 16);
        pfb_fused_kernel<<<grid, 256, 0, stream>>>(gre, gim, glpf, out);
    }
}

// Round 7
// 62.615 us; speedup vs baseline: 1.8409x; 1.8409x over previous
//
#include <hip/hip_runtime.h>
#include <hip/hip_bf16.h>
#include <math.h>

#define NBINS   129
#define NFFT    256
#define WINL    768
#define TFRAMES 4096
#define OUTL    523640          // 4096*128 - 648
#define SHIFT   648
#define WSEG    26
#define CHUNK   (WSEG * 128)
#define NCHUNK  ((OUTL + CHUNK - 1) / CHUNK)   // 158
#define FF      32

#define KDIM    288             // 258 real K padded to 9*32
#define KROW    296             // B row stride (ushorts)
#define GROW    268             // fused-path G row stride
#define WBYTES  (16 * 9 * 64 * 16)           // 147456 B packed twiddles
#define GBYTES  ((size_t)16 * TFRAMES * 256 * 2)  // 33.55 MB G buffer
#define NSTG    17

typedef __attribute__((ext_vector_type(8))) short bf16x8;
typedef __attribute__((ext_vector_type(4))) float f32x4;

static __device__ __forceinline__ ushort f2bf(float x) {
    union { float f; unsigned u; } v; v.f = x;
    unsigned r = v.u + 0x7FFFu + ((v.u >> 16) & 1u);
    return (ushort)(r >> 16);
}

// ---- pre-kernel: W[m][kappa] packed in mfma A-fragment order ----------------
__global__ void build_w_kernel(ushort* __restrict__ wp)
{
    const int gid  = blockIdx.x * 256 + threadIdx.x;    // 0..9215
    const int lane = gid & 63;
    const int mtks = gid >> 6;
    const int ks   = mtks % 9;
    const int mt   = mtks / 9;
    const int m    = mt * 16 + (lane & 15);
    const int kb   = ks * 32 + ((lane >> 4) << 3);

    ushort o[8];
    #pragma unroll
    for (int e = 0; e < 8; ++e) {
        const int kap = kb + e;
        float val = 0.f;
        if (kap < 258) {
            const int k = kap >> 1;
            float s, c;
            sincospif((float)(k * (m + 1)) * (1.0f / 128.0f), &s, &c);
            if (kap & 1)  val = (k >= 1 && k <= 127) ? s * (2.0f / 256.0f) : 0.f;
            else          val = (k == 0 || k == 128) ? c * (1.0f / 256.0f)
                                                     : c * (2.0f / 256.0f);
        }
        o[e] = f2bf(val);
    }
    int4 pk;
    pk.x = o[0] | (o[1] << 16); pk.y = o[2] | (o[3] << 16);
    pk.z = o[4] | (o[5] << 16); pk.w = o[6] | (o[7] << 16);
    ((int4*)wp)[gid] = pk;
}

// ---- kernel A: DFT GEMM, 32 frames/block, no halo, G -> d_ws ----------------
__global__ __launch_bounds__(256, 4)
void pfb_dft_kernel(const float* __restrict__ gre, const float* __restrict__ gim,
                    const ushort* __restrict__ wp, ushort* __restrict__ Gg)
{
    __shared__ ushort s_bufu[FF * KROW];               // 18944 B
    ushort* s_Bu = s_bufu;
    ushort (*s_G)[NFFT] = (ushort (*)[NFFT])s_bufu;    // 32*256*2 = 16384 B (aliased)

    const int t0  = blockIdx.x * FF;
    const int bc  = blockIdx.y;
    const int tid = threadIdx.x;
    const size_t specBase = (size_t)bc * NBINS * TFRAMES;

    // stage: all 34 loads issued, then LDS writes (t always < TFRAMES here)
    float vr[NSTG], vi[NSTG];
    #pragma unroll
    for (int r = 0; r < NSTG; ++r) {
        const int idx = tid + r * 256;
        float a = 0.f, b = 0.f;
        if (idx < NBINS * FF) {
            const int k = idx >> 5, f = idx & 31;
            const size_t g = specBase + (size_t)k * TFRAMES + (size_t)(t0 + f);
            a = gre[g]; b = gim[g];
        }
        vr[r] = a; vi[r] = b;
    }
    #pragma unroll
    for (int r = 0; r < NSTG; ++r) {
        const int idx = tid + r * 256;
        if (idx < NBINS * FF) {
            const int k = idx >> 5, f = idx & 31;
            __hip_bfloat162 p = __float22bfloat162_rn(make_float2(vr[r], vi[r]));
            *(__hip_bfloat162*)&s_Bu[f * KROW + 2 * k] = p;
        }
    }
    for (int idx = tid; idx < FF * (KROW - 258); idx += 256) {
        const int f = idx / (KROW - 258), r = idx - f * (KROW - 258);
        s_Bu[f * KROW + 258 + r] = 0;
    }
    __syncthreads();

    // GEMM: G[256][32] = W[256][288] x B[288][32]
    const int lane = tid & 63;
    const int wid  = tid >> 6;
    const int brow = lane & 15;
    const int kgrp = (lane >> 4) << 3;

    bf16x8 bfrag[2][9];
    #pragma unroll
    for (int nt = 0; nt < 2; ++nt)
        #pragma unroll
        for (int ks = 0; ks < 9; ++ks)
            bfrag[nt][ks] = *(const bf16x8*)&s_Bu[(nt * 16 + brow) * KROW + ks * 32 + kgrp];

    f32x4 acc[4][2];
    #pragma unroll
    for (int mi = 0; mi < 4; ++mi)
        #pragma unroll
        for (int nt = 0; nt < 2; ++nt)
            acc[mi][nt] = (f32x4){0.f, 0.f, 0.f, 0.f};

    #pragma unroll 1
    for (int mi = 0; mi < 4; ++mi) {
        const ushort* wbase = wp + ((size_t)((wid * 4 + mi) * 9) * 64 + lane) * 8;
        #pragma unroll
        for (int ks = 0; ks < 9; ++ks) {
            const bf16x8 aw = *(const bf16x8*)(wbase + ks * 512);
            acc[mi][0] = __builtin_amdgcn_mfma_f32_16x16x32_bf16(aw, bfrag[0][ks], acc[mi][0], 0, 0, 0);
            acc[mi][1] = __builtin_amdgcn_mfma_f32_16x16x32_bf16(aw, bfrag[1][ks], acc[mi][1], 0, 0, 0);
        }
    }
    __syncthreads();   // B consumed; alias with s_G

    // D layout: col(frame)=lane&15, row(m)=(lane>>4)*4+e
    #pragma unroll
    for (int mi = 0; mi < 4; ++mi) {
        const int m0 = (wid * 4 + mi) * 16 + ((lane >> 4) << 2);
        #pragma unroll
        for (int nt = 0; nt < 2; ++nt) {
            const int f = nt * 16 + brow;
            __hip_bfloat162 lo = __float22bfloat162_rn(make_float2(acc[mi][nt].x, acc[mi][nt].y));
            __hip_bfloat162 hi = __float22bfloat162_rn(make_float2(acc[mi][nt].z, acc[mi][nt].w));
            uint2 pk; pk.x = *(unsigned*)&lo; pk.y = *(unsigned*)&hi;
            *(uint2*)&s_G[f][m0] = pk;
        }
    }
    __syncthreads();

    // coalesced contiguous writeback: 32 frames x 256 = 16 KB
    ushort* gout = Gg + ((size_t)bc * TFRAMES + t0) * NFFT;
    #pragma unroll
    for (int j = 0; j < 4; ++j) {
        const int c   = tid + j * 256;        // 16B chunk id, < 1024
        const int row = c >> 5;
        const int col = (c & 31) * 8;
        *(bf16x8*)&gout[c * 8] = *(const bf16x8*)&s_G[row][col];
    }
}

// ---- kernel B: overlap-add streamer ----------------------------------------
__global__ __launch_bounds__(256, 8)
void pfb_oa_kernel(const ushort* __restrict__ Gg, const float* __restrict__ glpf,
                   float* __restrict__ out)
{
    const int tid = threadIdx.x;
    const int bc  = blockIdx.y;
    const int i0  = blockIdx.x * 2048 + tid;

    const int s0 = i0 + SHIFT;
    const int b  = s0 & 127;
    float lw[6];
    #pragma unroll
    for (int p = 0; p < 6; ++p) lw[p] = glpf[(p << 7) + b];

    const ushort* Gb = Gg + (size_t)bc * TFRAMES * NFFT;
    const size_t outBase = (size_t)bc * OUTL;

    #pragma unroll
    for (int j = 0; j < 8; ++j) {
        const int i = i0 + j * 256;
        if (i < OUTL) {
            const int a = (i + SHIFT) >> 7;
            const ushort* gp = Gb + (size_t)a * NFFT + b;
            float sum = 0.f;
            #pragma unroll
            for (int p = 0; p < 6; ++p) {
                union { unsigned u_; float f; } g;
                g.u_ = ((unsigned)gp[-(p << 8) + ((p & 1) << 7)]) << 16;
                sum += lw[p] * g.f;
            }
            out[outBase + i] = sum * (-32768.0f);
        }
    }
}

// ---- fused fallback (round-5, 80.5 us known-good) ---------------------------
__global__ __launch_bounds__(256, 4)
void pfb_mfma_kernel(const float* __restrict__ gre, const float* __restrict__ gim,
                     const float* __restrict__ glpf, const ushort* __restrict__ wp,
                     float* __restrict__ out)
{
    __shared__ ushort s_bufu[FF * KROW];
    __shared__ float  s_lpf[WINL];
    ushort* s_Bu = s_bufu;
    ushort (*s_G)[GROW] = (ushort (*)[GROW])s_bufu;

    const int q   = blockIdx.x;
    const int bc  = blockIdx.y;
    const int tid = threadIdx.x;
    const int t0  = WSEG * q;
    const size_t specBase = (size_t)bc * NBINS * TFRAMES;

    for (int idx = tid; idx < WINL; idx += 256) s_lpf[idx] = glpf[idx];

    float vr[NSTG], vi[NSTG];
    #pragma unroll
    for (int r = 0; r < NSTG; ++r) {
        const int idx = tid + r * 256;
        const int k = idx >> 5, f = idx & 31;
        const int t = t0 + f;
        const bool ok = (idx < NBINS * FF) && (t < TFRAMES);
        float a = 0.f, bb = 0.f;
        if (ok) {
            const size_t g = specBase + (size_t)k * TFRAMES + (size_t)t;
            a = gre[g]; bb = gim[g];
        }
        vr[r] = a; vi[r] = bb;
    }
    #pragma unroll
    for (int r = 0; r < NSTG; ++r) {
        const int idx = tid + r * 256;
        if (idx < NBINS * FF) {
            const int k = idx >> 5, f = idx & 31;
            __hip_bfloat162 p = __float22bfloat162_rn(make_float2(vr[r], vi[r]));
            *(__hip_bfloat162*)&s_Bu[f * KROW + 2 * k] = p;
        }
    }
    for (int idx = tid; idx < FF * (KROW - 258); idx += 256) {
        const int f = idx / (KROW - 258), r = idx - f * (KROW - 258);
        s_Bu[f * KROW + 258 + r] = 0;
    }
    __syncthreads();

    const int lane = tid & 63;
    const int wid  = tid >> 6;
    const int brow = lane & 15;
    const int kgrp = (lane >> 4) << 3;

    bf16x8 bfrag[2][9];
    #pragma unroll
    for (int nt = 0; nt < 2; ++nt)
        #pragma unroll
        for (int ks = 0; ks < 9; ++ks)
            bfrag[nt][ks] = *(const bf16x8*)&s_Bu[(nt * 16 + brow) * KROW + ks * 32 + kgrp];

    f32x4 acc[4][2];
    #pragma unroll
    for (int mi = 0; mi < 4; ++mi)
        #pragma unroll
        for (int nt = 0; nt < 2; ++nt)
            acc[mi][nt] = (f32x4){0.f, 0.f, 0.f, 0.f};

    #pragma unroll 1
    for (int mi = 0; mi < 4; ++mi) {
        const ushort* wbase = wp + ((size_t)((wid * 4 + mi) * 9) * 64 + lane) * 8;
        #pragma unroll
        for (int ks = 0; ks < 9; ++ks) {
            const bf16x8 aw = *(const bf16x8*)(wbase + ks * 512);
            acc[mi][0] = __builtin_amdgcn_mfma_f32_16x16x32_bf16(aw, bfrag[0][ks], acc[mi][0], 0, 0, 0);
            acc[mi][1] = __builtin_amdgcn_mfma_f32_16x16x32_bf16(aw, bfrag[1][ks], acc[mi][1], 0, 0, 0);
        }
    }
    __syncthreads();

    #pragma unroll
    for (int mi = 0; mi < 4; ++mi) {
        const int m0 = (wid * 4 + mi) * 16 + ((lane >> 4) << 2);
        #pragma unroll
        for (int nt = 0; nt < 2; ++nt) {
            const int f = nt * 16 + brow;
            __hip_bfloat162 lo = __float22bfloat162_rn(make_float2(acc[mi][nt].x, acc[mi][nt].y));
            __hip_bfloat162 hi = __float22bfloat162_rn(make_float2(acc[mi][nt].z, acc[mi][nt].w));
            uint2 pk; pk.x = *(unsigned*)&lo; pk.y = *(unsigned*)&hi;
            *(uint2*)&s_G[f][m0] = pk;
        }
    }
    __syncthreads();

    const size_t outBase = (size_t)bc * OUTL;
    const int i0 = q * CHUNK;
    #pragma unroll 1
    for (int r = 0; r < 13; ++r) {
        const int i = i0 + r * 256 + tid;
        const int s = i + SHIFT;
        const int tlo = (s - 640) >> 7;
        int thi = s >> 7;
        if (thi > t0 + FF - 1) thi = t0 + FF - 1;
        if (thi > TFRAMES - 1) thi = TFRAMES - 1;
        float sum = 0.f;
        #pragma unroll
        for (int u = 0; u < 6; ++u) {
            const int t  = tlo + u;
            int jj = s - (t << 7);
            if (jj < 0) jj = 0;
            const float w = s_lpf[jj];
            union { unsigned u_; float f; } g;
            g.u_ = ((unsigned)s_G[t - t0][jj & 255]) << 16;
            sum += (t <= thi) ? w * g.f : 0.f;
        }
        if (i < OUTL) out[outBase + i] = sum * (-32768.0f);
    }
}

extern "C" void kernel_launch(void* const* d_in, const int* in_sizes, int n_in,
                              void* d_out, int out_size, void* d_ws, size_t ws_size,
                              hipStream_t stream)
{
    const float* gre  = (const float*)d_in[0];
    const float* gim  = (const float*)d_in[1];
    const float* glpf = (const float*)d_in[2];
    float* out = (float*)d_out;

    if (ws_size >= (size_t)WBYTES + GBYTES) {
        ushort* wp = (ushort*)d_ws;
        ushort* Gg = (ushort*)((char*)d_ws + WBYTES);
        build_w_kernel<<<36, 256, 0, stream>>>(wp);
        dim3 gridA(TFRAMES / FF, 16);                 // 128 x 16
        pfb_dft_kernel<<<gridA, 256, 0, stream>>>(gre, gim, wp, Gg);
        dim3 gridB((OUTL + 2047) / 2048, 16);         // 256 x 16
        pfb_oa_kernel<<<gridB, 256, 0, stream>>>(Gg, glpf, out);
    } else if (ws_size >= (size_t)WBYTES) {
        ushort* wp = (ushort*)d_ws;
        build_w_kernel<<<36, 256, 0, stream>>>(wp);
        dim3 grid(NCHUNK, 16);
        pfb_mfma_kernel<<<grid, 256, 0, stream>>>(gre, gim, glpf, wp, out);
    }
}

// Round 8
// 56.362 us; speedup vs baseline: 2.0452x; 1.1110x over previous
//
#include <hip/hip_runtime.h>
#include <hip/hip_bf16.h>
#include <math.h>

#define NBINS   129
#define NFFT    256
#define WINL    768
#define TFRAMES 4096
#define OUTL    523640          // 4096*128 - 648
#define NPAIRS  (OUTL / 2)      // 261820
#define SHIFT   648
#define WSEG    26
#define CHUNK   (WSEG * 128)
#define NCHUNK  ((OUTL + CHUNK - 1) / CHUNK)   // 158
#define FF      32

#define KDIM    288             // 258 real K padded to 9*32
#define KROW    296             // B row stride (ushorts)
#define GROW    268             // fused-path G row stride
#define WBYTES  (16 * 9 * 64 * 16)               // 147456 B packed twiddles
#define GBYTES  ((size_t)16 * TFRAMES * 256 * 2) // 33.55 MB G buffer
#define NSTG    17

typedef __attribute__((ext_vector_type(8))) short bf16x8;
typedef __attribute__((ext_vector_type(4))) float f32x4;

static __device__ __forceinline__ ushort f2bf(float x) {
    union { float f; unsigned u; } v; v.f = x;
    unsigned r = v.u + 0x7FFFu + ((v.u >> 16) & 1u);
    return (ushort)(r >> 16);
}

// ---- pre-kernel: W[m][kappa] packed in mfma A-fragment order ----------------
__global__ void build_w_kernel(ushort* __restrict__ wp)
{
    const int gid  = blockIdx.x * 256 + threadIdx.x;    // 0..9215
    const int lane = gid & 63;
    const int mtks = gid >> 6;
    const int ks   = mtks % 9;
    const int mt   = mtks / 9;
    const int m    = mt * 16 + (lane & 15);
    const int kb   = ks * 32 + ((lane >> 4) << 3);

    ushort o[8];
    #pragma unroll
    for (int e = 0; e < 8; ++e) {
        const int kap = kb + e;
        float val = 0.f;
        if (kap < 258) {
            const int k = kap >> 1;
            float s, c;
            sincospif((float)(k * (m + 1)) * (1.0f / 128.0f), &s, &c);
            if (kap & 1)  val = (k >= 1 && k <= 127) ? s * (2.0f / 256.0f) : 0.f;
            else          val = (k == 0 || k == 128) ? c * (1.0f / 256.0f)
                                                     : c * (2.0f / 256.0f);
        }
        o[e] = f2bf(val);
    }
    int4 pk;
    pk.x = o[0] | (o[1] << 16); pk.y = o[2] | (o[3] << 16);
    pk.z = o[4] | (o[5] << 16); pk.w = o[6] | (o[7] << 16);
    ((int4*)wp)[gid] = pk;
}

// ---- kernel A: DFT GEMM, 32 frames/block, direct global D-write -------------
__global__ __launch_bounds__(256, 6)
void pfb_dft_kernel(const float* __restrict__ gre, const float* __restrict__ gim,
                    const ushort* __restrict__ wp, ushort* __restrict__ Gg)
{
    __shared__ ushort s_Bu[FF * KROW];                 // 18944 B

    const int t0  = blockIdx.x * FF;
    const int bc  = blockIdx.y;
    const int tid = threadIdx.x;
    const size_t specBase = (size_t)bc * NBINS * TFRAMES;

    // stage: all 34 loads issued, then LDS writes
    float vr[NSTG], vi[NSTG];
    #pragma unroll
    for (int r = 0; r < NSTG; ++r) {
        const int idx = tid + r * 256;
        float a = 0.f, b = 0.f;
        if (idx < NBINS * FF) {
            const int k = idx >> 5, f = idx & 31;
            const size_t g = specBase + (size_t)k * TFRAMES + (size_t)(t0 + f);
            a = gre[g]; b = gim[g];
        }
        vr[r] = a; vi[r] = b;
    }
    #pragma unroll
    for (int r = 0; r < NSTG; ++r) {
        const int idx = tid + r * 256;
        if (idx < NBINS * FF) {
            const int k = idx >> 5, f = idx & 31;
            __hip_bfloat162 p = __float22bfloat162_rn(make_float2(vr[r], vi[r]));
            *(__hip_bfloat162*)&s_Bu[f * KROW + 2 * k] = p;
        }
    }
    for (int idx = tid; idx < FF * (KROW - 258); idx += 256) {
        const int f = idx / (KROW - 258), r = idx - f * (KROW - 258);
        s_Bu[f * KROW + 258 + r] = 0;
    }
    __syncthreads();

    // GEMM: G[256][32] = W[256][288] x B[288][32], ks-outer (fits registers)
    const int lane = tid & 63;
    const int wid  = tid >> 6;
    const int brow = lane & 15;
    const int kgrp = (lane >> 4) << 3;

    f32x4 acc[4][2];
    #pragma unroll
    for (int mi = 0; mi < 4; ++mi)
        #pragma unroll
        for (int nt = 0; nt < 2; ++nt)
            acc[mi][nt] = (f32x4){0.f, 0.f, 0.f, 0.f};

    const ushort* wbase0 = wp + ((size_t)(wid * 4) * 9 * 64 + (size_t)lane) * 8;
    #pragma unroll
    for (int ks = 0; ks < 9; ++ks) {
        const bf16x8 b0 = *(const bf16x8*)&s_Bu[brow * KROW + ks * 32 + kgrp];
        const bf16x8 b1 = *(const bf16x8*)&s_Bu[(16 + brow) * KROW + ks * 32 + kgrp];
        #pragma unroll
        for (int mi = 0; mi < 4; ++mi) {
            const bf16x8 aw = *(const bf16x8*)(wbase0 + mi * 4608 + ks * 512);
            acc[mi][0] = __builtin_amdgcn_mfma_f32_16x16x32_bf16(aw, b0, acc[mi][0], 0, 0, 0);
            acc[mi][1] = __builtin_amdgcn_mfma_f32_16x16x32_bf16(aw, b1, acc[mi][1], 0, 0, 0);
        }
    }

    // direct global writeback: D row f = frame, cols m0..m0+3 (8B per store;
    // 4 consecutive lanes form 32B segments, L2 merges to full lines)
    ushort* gout = Gg + ((size_t)bc * TFRAMES + t0) * NFFT;
    #pragma unroll
    for (int mi = 0; mi < 4; ++mi) {
        const int m0 = (wid * 4 + mi) * 16 + ((lane >> 4) << 2);
        #pragma unroll
        for (int nt = 0; nt < 2; ++nt) {
            const int f = nt * 16 + brow;
            __hip_bfloat162 lo = __float22bfloat162_rn(make_float2(acc[mi][nt].x, acc[mi][nt].y));
            __hip_bfloat162 hi = __float22bfloat162_rn(make_float2(acc[mi][nt].z, acc[mi][nt].w));
            uint2 pk; pk.x = *(unsigned*)&lo; pk.y = *(unsigned*)&hi;
            *(uint2*)&gout[f * NFFT + m0] = pk;
        }
    }
}

// ---- kernel B: overlap-add streamer, 2 outputs/thread -----------------------
__global__ __launch_bounds__(256, 8)
void pfb_oa_kernel(const ushort* __restrict__ Gg, const float* __restrict__ glpf,
                   float* __restrict__ out)
{
    const int tid = threadIdx.x;
    const int bc  = blockIdx.y;
    const int g0  = blockIdx.x * 1024 + tid;       // pair index

    const int b = (2 * g0 + SHIFT) & 127;          // even; invariant over j
    float2 lw[6];
    #pragma unroll
    for (int p = 0; p < 6; ++p) lw[p] = *(const float2*)&glpf[(p << 7) + b];

    const ushort* Gb = Gg + (size_t)bc * TFRAMES * NFFT;
    const size_t outBase = (size_t)bc * OUTL;

    #pragma unroll
    for (int j = 0; j < 4; ++j) {
        const int g = g0 + j * 256;
        int a = (2 * g + SHIFT) >> 7;
        if (a > TFRAMES - 1) a = TFRAMES - 1;      // clamp keeps loads in-bounds
        float sx = 0.f, sy = 0.f;
        #pragma unroll
        for (int p = 0; p < 6; ++p) {
            const unsigned pr = *(const unsigned*)&Gb[(size_t)(a - p) * NFFT + b + ((p & 1) << 7)];
            union { unsigned u; float f; } glo, ghi;
            glo.u = pr << 16;
            ghi.u = pr & 0xFFFF0000u;
            sx += lw[p].x * glo.f;
            sy += lw[p].y * ghi.f;
        }
        if (g < NPAIRS) {
            float2 o; o.x = sx * (-32768.0f); o.y = sy * (-32768.0f);
            *(float2*)&out[outBase + 2 * g] = o;
        }
    }
}

// ---- fused fallback (round-5 path, used only if ws too small) ---------------
__global__ __launch_bounds__(256, 4)
void pfb_mfma_kernel(const float* __restrict__ gre, const float* __restrict__ gim,
                     const float* __restrict__ glpf, const ushort* __restrict__ wp,
                     float* __restrict__ out)
{
    __shared__ ushort s_bufu[FF * KROW];
    __shared__ float  s_lpf[WINL];
    ushort* s_Bu = s_bufu;
    ushort (*s_G)[GROW] = (ushort (*)[GROW])s_bufu;

    const int q   = blockIdx.x;
    const int bc  = blockIdx.y;
    const int tid = threadIdx.x;
    const int t0  = WSEG * q;
    const size_t specBase = (size_t)bc * NBINS * TFRAMES;

    for (int idx = tid; idx < WINL; idx += 256) s_lpf[idx] = glpf[idx];

    float vr[NSTG], vi[NSTG];
    #pragma unroll
    for (int r = 0; r < NSTG; ++r) {
        const int idx = tid + r * 256;
        const int k = idx >> 5, f = idx & 31;
        const int t = t0 + f;
        const bool ok = (idx < NBINS * FF) && (t < TFRAMES);
        float a = 0.f, bb = 0.f;
        if (ok) {
            const size_t g = specBase + (size_t)k * TFRAMES + (size_t)t;
            a = gre[g]; bb = gim[g];
        }
        vr[r] = a; vi[r] = bb;
    }
    #pragma unroll
    for (int r = 0; r < NSTG; ++r) {
        const int idx = tid + r * 256;
        if (idx < NBINS * FF) {
            const int k = idx >> 5, f = idx & 31;
            __hip_bfloat162 p = __float22bfloat162_rn(make_float2(vr[r], vi[r]));
            *(__hip_bfloat162*)&s_Bu[f * KROW + 2 * k] = p;
        }
    }
    for (int idx = tid; idx < FF * (KROW - 258); idx += 256) {
        const int f = idx / (KROW - 258), r = idx - f * (KROW - 258);
        s_Bu[f * KROW + 258 + r] = 0;
    }
    __syncthreads();

    const int lane = tid & 63;
    const int wid  = tid >> 6;
    const int brow = lane & 15;
    const int kgrp = (lane >> 4) << 3;

    bf16x8 bfrag[2][9];
    #pragma unroll
    for (int nt = 0; nt < 2; ++nt)
        #pragma unroll
        for (int ks = 0; ks < 9; ++ks)
            bfrag[nt][ks] = *(const bf16x8*)&s_Bu[(nt * 16 + brow) * KROW + ks * 32 + kgrp];

    f32x4 acc[4][2];
    #pragma unroll
    for (int mi = 0; mi < 4; ++mi)
        #pragma unroll
        for (int nt = 0; nt < 2; ++nt)
            acc[mi][nt] = (f32x4){0.f, 0.f, 0.f, 0.f};

    #pragma unroll 1
    for (int mi = 0; mi < 4; ++mi) {
        const ushort* wbase = wp + ((size_t)((wid * 4 + mi) * 9) * 64 + lane) * 8;
        #pragma unroll
        for (int ks = 0; ks < 9; ++ks) {
            const bf16x8 aw = *(const bf16x8*)(wbase + ks * 512);
            acc[mi][0] = __builtin_amdgcn_mfma_f32_16x16x32_bf16(aw, bfrag[0][ks], acc[mi][0], 0, 0, 0);
            acc[mi][1] = __builtin_amdgcn_mfma_f32_16x16x32_bf16(aw, bfrag[1][ks], acc[mi][1], 0, 0, 0);
        }
    }
    __syncthreads();

    #pragma unroll
    for (int mi = 0; mi < 4; ++mi) {
        const int m0 = (wid * 4 + mi) * 16 + ((lane >> 4) << 2);
        #pragma unroll
        for (int nt = 0; nt < 2; ++nt) {
            const int f = nt * 16 + brow;
            __hip_bfloat162 lo = __float22bfloat162_rn(make_float2(acc[mi][nt].x, acc[mi][nt].y));
            __hip_bfloat162 hi = __float22bfloat162_rn(make_float2(acc[mi][nt].z, acc[mi][nt].w));
            uint2 pk; pk.x = *(unsigned*)&lo; pk.y = *(unsigned*)&hi;
            *(uint2*)&s_G[f][m0] = pk;
        }
    }
    __syncthreads();

    const size_t outBase = (size_t)bc * OUTL;
    const int i0 = q * CHUNK;
    #pragma unroll 1
    for (int r = 0; r < 13; ++r) {
        const int i = i0 + r * 256 + tid;
        const int s = i + SHIFT;
        const int tlo = (s - 640) >> 7;
        int thi = s >> 7;
        if (thi > t0 + FF - 1) thi = t0 + FF - 1;
        if (thi > TFRAMES - 1) thi = TFRAMES - 1;
        float sum = 0.f;
        #pragma unroll
        for (int u = 0; u < 6; ++u) {
            const int t  = tlo + u;
            int jj = s - (t << 7);
            if (jj < 0) jj = 0;
            const float w = s_lpf[jj];
            union { unsigned u_; float f; } g;
            g.u_ = ((unsigned)s_G[t - t0][jj & 255]) << 16;
            sum += (t <= thi) ? w * g.f : 0.f;
        }
        if (i < OUTL) out[outBase + i] = sum * (-32768.0f);
    }
}

extern "C" void kernel_launch(void* const* d_in, const int* in_sizes, int n_in,
                              void* d_out, int out_size, void* d_ws, size_t ws_size,
                              hipStream_t stream)
{
    const float* gre  = (const float*)d_in[0];
    const float* gim  = (const float*)d_in[1];
    const float* glpf = (const float*)d_in[2];
    float* out = (float*)d_out;

    if (ws_size >= (size_t)WBYTES + GBYTES) {
        ushort* wp = (ushort*)d_ws;
        ushort* Gg = (ushort*)((char*)d_ws + WBYTES);
        build_w_kernel<<<36, 256, 0, stream>>>(wp);
        dim3 gridA(TFRAMES / FF, 16);                 // 128 x 16
        pfb_dft_kernel<<<gridA, 256, 0, stream>>>(gre, gim, wp, Gg);
        dim3 gridB((NPAIRS + 1023) / 1024, 16);       // 256 x 16
        pfb_oa_kernel<<<gridB, 256, 0, stream>>>(Gg, glpf, out);
    } else if (ws_size >= (size_t)WBYTES) {
        ushort* wp = (ushort*)d_ws;
        build_w_kernel<<<36, 256, 0, stream>>>(wp);
        dim3 grid(NCHUNK, 16);
        pfb_mfma_kernel<<<grid, 256, 0, stream>>>(gre, gim, glpf, wp, out);
    }
}